// Round 13
// baseline (213.442 us; speedup 1.0000x reference)
//
#include <hip/hip_runtime.h>
#include <math.h>

#define B_ 2
#define S_ 2048
#define E_ 1024
#define H_ 16
#define D_ 64
#define M_ (B_*S_)
#define PT 32

typedef short bf16x8 __attribute__((ext_vector_type(8)));
typedef float f32x4 __attribute__((ext_vector_type(4)));
typedef unsigned short u16x4 __attribute__((ext_vector_type(4)));

__device__ __forceinline__ unsigned short f2bf(float f) {
    unsigned int u = __builtin_bit_cast(unsigned int, f);
    u += 0x7FFFu + ((u >> 16) & 1u);
    return (unsigned short)(u >> 16);
}
__device__ __forceinline__ f32x4 mfma16(bf16x8 a, bf16x8 b, f32x4 c) {
    return __builtin_amdgcn_mfma_f32_16x16x32_bf16(a, b, c, 0, 0, 0);
}
__device__ __forceinline__ bf16x8 cvt8(const float* p) {
    f32x4 lo = *(const f32x4*)p;
    f32x4 hi = *(const f32x4*)(p + 4);
    bf16x8 r;
#pragma unroll
    for (int e = 0; e < 4; e++) { r[e] = (short)f2bf(lo[e]); r[e + 4] = (short)f2bf(hi[e]); }
    return r;
}
__device__ __forceinline__ void g2l16(const unsigned short* g, unsigned short* l) {
    __builtin_amdgcn_global_load_lds(
        (const __attribute__((address_space(1))) unsigned int*)(const void*)g,
        (__attribute__((address_space(3))) unsigned int*)(void*)l,
        16, 0, 0);
}

// ---------------- Kernel 0: f32 -> bf16 conversion (X + 4 weights) ----------
__global__ __launch_bounds__(256) void cvt_kernel(
    const float* __restrict__ X,  const float* __restrict__ Wq,
    const float* __restrict__ Wk, const float* __restrict__ Wv,
    const float* __restrict__ Wo,
    unsigned short* __restrict__ Xb, unsigned short* __restrict__ Wb)
{
    const int y = blockIdx.y;
    const float* src = (y == 0) ? X : (y == 1) ? Wq : (y == 2) ? Wk : (y == 3) ? Wv : Wo;
    unsigned short* dst = (y == 0) ? Xb : Wb + (size_t)(y - 1) * (E_ * E_);
    const size_t n = (y == 0) ? (size_t)M_ * E_ : (size_t)E_ * E_;
    size_t i = ((size_t)blockIdx.x * 256 + threadIdx.x) * 8;
    if (i < n) *(bf16x8*)(dst + i) = cvt8(src + i);
}

// ---------------- Kernel 1: QKV proj + RoPE (bf16, g2l16) -------------------
__global__ __launch_bounds__(256, 4) void qkv_rope_bf(
    const unsigned short* __restrict__ Xb, const unsigned short* __restrict__ Wb,
    const float* __restrict__ bq, const float* __restrict__ bk,
    const float* __restrict__ bv,
    unsigned short* __restrict__ Qo, unsigned short* __restrict__ Ko,
    unsigned short* __restrict__ Vo)
{
    __shared__ __align__(16) unsigned char lds_raw[128 * 132 * 2];
    unsigned short* As = (unsigned short*)lds_raw;
    unsigned short* Bs = (unsigned short*)(lds_raw + 8192);
    unsigned short* Cs = (unsigned short*)lds_raw;

    const int t = threadIdx.x;
    const int w = t >> 6, lane = t & 63, quad = lane >> 4, l16 = lane & 15;
    const int wr = (w >> 1) * 64, wc = (w & 1) * 64;
    const int n0 = blockIdx.x * 128, m0 = blockIdx.y * 128;
    const int z = blockIdx.z;
    const unsigned short* W = Wb + (size_t)z * (E_ * E_);
    const float* bias = (z == 0) ? bq : (z == 1) ? bk : bv;

    const int r4 = t >> 2, c8 = (t & 3) * 8;
    const unsigned short* Ag = Xb + (size_t)(m0 + r4) * E_ + c8;
    const unsigned short* Bg = W  + (size_t)(n0 + r4) * E_ + c8;

    f32x4 zero = {0.f, 0.f, 0.f, 0.f};
    f32x4 acc[4][4];
#pragma unroll
    for (int i = 0; i < 4; i++)
#pragma unroll
        for (int j = 0; j < 4; j++) acc[i][j] = zero;

    for (int kt = 0; kt < E_; kt += 32) {
        __syncthreads();
        g2l16(Ag + kt,           &As[t * 8]);
        g2l16(Ag + 64 * E_ + kt, &As[t * 8 + 2048]);
        g2l16(Bg + kt,           &Bs[t * 8]);
        g2l16(Bg + 64 * E_ + kt, &Bs[t * 8 + 2048]);
        __syncthreads();
        bf16x8 af[4], bfr[4];
#pragma unroll
        for (int i = 0; i < 4; i++)
            af[i] = *(const bf16x8*)&As[(wr + i * 16 + l16) * 32 + quad * 8];
#pragma unroll
        for (int j = 0; j < 4; j++)
            bfr[j] = *(const bf16x8*)&Bs[(wc + j * 16 + l16) * 32 + quad * 8];
#pragma unroll
        for (int i = 0; i < 4; i++)
#pragma unroll
            for (int j = 0; j < 4; j++)
                acc[i][j] = mfma16(af[i], bfr[j], acc[i][j]);
    }

    __syncthreads();
    const int seg = quad;
    if (z < 2) {
        const float C = -0.41524101186091903f;
        const float INV2PI = 0.15915494309189535f;
#pragma unroll
        for (int j = 0; j < 4; j++) {
            int n_local = wc + j * 16 + l16;
            int n = n0 + n_local;
            int d = n & 63, f = d >> 1;
            float inv_rev = exp2f(C * (float)f) * INV2PI;
            float bvv = bias[n];
            float sgn = (d & 1) ? 1.f : -1.f;
#pragma unroll
            for (int i = 0; i < 4; i++) {
                int mb = wr + i * 16 + quad * 4;
#pragma unroll
                for (int r = 0; r < 4; r++) {
                    int m = m0 + mb + r;
                    int s = m & (S_ - 1);
                    float val = acc[i][j][r] + bvv;
                    float oth = __shfl_xor(val, 1);
                    float rev = (float)s * inv_rev;
                    float fr = rev - rintf(rev);
                    float sn = __builtin_amdgcn_sinf(fr);
                    float cs = __builtin_amdgcn_cosf(fr);
                    Cs[(mb + r) * 132 + n_local] = f2bf(val * cs + sgn * oth * sn);
                }
            }
        }
        __syncthreads();
        unsigned short* Out = (z == 0) ? Qo : Ko;
        const int btok = m0 >> 11;
        const int half = seg & 1;
#pragma unroll
        for (int it = 0; it < 16; it++) {
            int m_local = it * 8 + w * 2 + (seg >> 1);
            int s = (m0 + m_local) & (S_ - 1);
            int h = (n0 + half * 64) >> 6;
            u16x4 v = *(const u16x4*)&Cs[m_local * 132 + half * 64 + l16 * 4];
            *(u16x4*)&Out[(((size_t)btok * H_ + h) * S_ + s) * D_ + l16 * 4] = v;
        }
    } else {
#pragma unroll
        for (int j = 0; j < 4; j++) {
            int n_local = wc + j * 16 + l16;
            float bvv = bias[n0 + n_local];
#pragma unroll
            for (int i = 0; i < 4; i++) {
                int mb = wr + i * 16 + quad * 4;
#pragma unroll
                for (int r = 0; r < 4; r++)
                    Cs[n_local * 132 + mb + r] = f2bf(acc[i][j][r] + bvv);
            }
        }
        __syncthreads();
        const int btok = m0 >> 11;
        const int s0 = m0 & (S_ - 1);
        const int half = seg & 1;
#pragma unroll
        for (int it = 0; it < 16; it++) {
            int n_local = it * 8 + w * 2 + (seg >> 1);
            int n = n0 + n_local;
            int h = n >> 6, d = n & 63;
            u16x4 v = *(const u16x4*)&Cs[n_local * 132 + half * 64 + l16 * 4];
            *(u16x4*)&Vo[(((size_t)btok * H_ + h) * D_ + d) * S_ + s0 + half * 64 + l16 * 4] = v;
        }
    }
}

// -------- attention core (shared by direct & split variants) ----------------
struct AttnAcc { f32x4 o[4]; f32x4 l; };
__device__ __forceinline__ AttnAcc attn_core(
    const unsigned short* Q, const unsigned short* K, const unsigned short* Vt,
    int bh, int q0, int kt_begin, int kt_end,
    unsigned short (*Ks)[64 * 32], unsigned short (*Vs)[64 * 32],
    unsigned short (*Ps)[16 * 72])
{
    const int t = threadIdx.x;
    const int w = t >> 6, lane = t & 63, quad = lane >> 4, l16 = lane & 15;

    const unsigned short* Qg = Q + ((size_t)bh * S_ + q0) * D_;
    bf16x8 qf[2];
#pragma unroll
    for (int ks = 0; ks < 2; ks++)
        qf[ks] = *(const bf16x8*)(Qg + (size_t)l16 * 64 + ks * 32 + quad * 8);

    bf16x8 ones;
#pragma unroll
    for (int e = 0; e < 8; e++) ones[e] = (short)0x3F80;

    f32x4 zero = {0.f, 0.f, 0.f, 0.f};
    AttnAcc A;
    A.l = zero;
#pragma unroll
    for (int j = 0; j < 4; j++) A.o[j] = zero;

    const int tt = t & 255, ksel = t >> 8;
    const int sr = tt >> 2, sc = (tt & 3) * 8;
    unsigned short* KsF = &Ks[0][0];
    unsigned short* VsF = &Vs[0][0];
    const unsigned short* Kg0 = K  + (size_t)bh * S_ * D_ + (size_t)sr * 64 + ksel * 32 + sc;
    const unsigned short* Vg0 = Vt + (size_t)bh * D_ * S_ + (size_t)sr * S_ + ksel * 32 + sc;

    const float SCL = 0.18033688011f;  // log2(e)/8

    for (int kt = kt_begin; kt < kt_end; kt += 64) {
        __syncthreads();
        g2l16(Kg0 + (size_t)kt * 64, &KsF[t * 8]);
        g2l16(Vg0 + kt,              &VsF[t * 8]);
        __syncthreads();

        f32x4 sc4[4];
#pragma unroll
        for (int j = 0; j < 4; j++) sc4[j] = zero;
#pragma unroll
        for (int ks = 0; ks < 2; ks++) {
#pragma unroll
            for (int j = 0; j < 4; j++) {
                bf16x8 kf = *(const bf16x8*)&Ks[ks][(j * 16 + l16) * 32 + quad * 8];
                sc4[j] = mfma16(qf[ks], kf, sc4[j]);
            }
        }
#pragma unroll
        for (int j = 0; j < 4; j++)
#pragma unroll
            for (int r = 0; r < 4; r++) {
                float p = __builtin_amdgcn_exp2f(sc4[j][r] * SCL);
                Ps[w][(quad * 4 + r) * 72 + j * 16 + l16] = f2bf(p);
            }
#pragma unroll
        for (int ks = 0; ks < 2; ks++) {
            bf16x8 pf = *(const bf16x8*)&Ps[w][l16 * 72 + ks * 32 + quad * 8];
#pragma unroll
            for (int jd = 0; jd < 4; jd++) {
                bf16x8 vf = *(const bf16x8*)&Vs[ks][(jd * 16 + l16) * 32 + quad * 8];
                A.o[jd] = mfma16(pf, vf, A.o[jd]);
            }
            A.l = mfma16(pf, ones, A.l);
        }
    }
    return A;
}

// ---------------- Kernel 2a: attention direct (ws-small path) ---------------
__global__ __launch_bounds__(512, 4) void attn_direct(
    const unsigned short* __restrict__ Q, const unsigned short* __restrict__ K,
    const unsigned short* __restrict__ Vt, unsigned short* __restrict__ ctx)
{
    __shared__ unsigned short Ks[2][64 * 32];
    __shared__ unsigned short Vs[2][64 * 32];
    __shared__ unsigned short Ps[8][16 * 72];
    const int t = threadIdx.x;
    const int w = t >> 6, lane = t & 63, quad = lane >> 4, l16 = lane & 15;
    const int bh = blockIdx.y;
    const int q0 = blockIdx.x * 128 + w * 16;

    AttnAcc A = attn_core(Q, K, Vt, bh, q0, 0, S_, Ks, Vs, Ps);

    const int b = bh >> 4, h = bh & 15;
    f32x4 rl;
#pragma unroll
    for (int r = 0; r < 4; r++) rl[r] = 1.0f / A.l[r];
#pragma unroll
    for (int jd = 0; jd < 4; jd++)
#pragma unroll
        for (int r = 0; r < 4; r++) {
            int qrow = q0 + quad * 4 + r;
            int col = h * 64 + jd * 16 + l16;
            ctx[((size_t)b * S_ + qrow) * E_ + col] = f2bf(A.o[jd][r] * rl[r]);
        }
}

// ---------------- Kernel 2b: attention split-K (z=half of keys) -------------
__global__ __launch_bounds__(512, 4) void attn_split(
    const unsigned short* __restrict__ Q, const unsigned short* __restrict__ K,
    const unsigned short* __restrict__ Vt,
    float* __restrict__ Op, float* __restrict__ Lp)
{
    __shared__ unsigned short Ks[2][64 * 32];
    __shared__ unsigned short Vs[2][64 * 32];
    __shared__ unsigned short Ps[8][16 * 72];
    const int t = threadIdx.x;
    const int w = t >> 6, lane = t & 63, quad = lane >> 4, l16 = lane & 15;
    const int bh = blockIdx.y;
    const int half = blockIdx.z;
    const int q0 = blockIdx.x * 128 + w * 16;

    AttnAcc A = attn_core(Q, K, Vt, bh, q0, half * (S_ / 2), (half + 1) * (S_ / 2),
                          Ks, Vs, Ps);

    const size_t base = ((size_t)half * (B_ * H_) + bh) * S_;
#pragma unroll
    for (int jd = 0; jd < 4; jd++)
#pragma unroll
        for (int r = 0; r < 4; r++) {
            int qrow = q0 + quad * 4 + r;
            Op[(base + qrow) * D_ + jd * 16 + l16] = A.o[jd][r];
        }
    if (l16 == 0) {
#pragma unroll
        for (int r = 0; r < 4; r++)
            Lp[base + q0 + quad * 4 + r] = A.l[r];
    }
}

// ---------------- Kernel 2c: combine partials -> ctx bf16 -------------------
__global__ __launch_bounds__(256) void combine_kernel(
    const float* __restrict__ Op, const float* __restrict__ Lp,
    unsigned short* __restrict__ ctx)
{
    const size_t TN = (size_t)B_ * H_ * S_ * D_;
    size_t i = ((size_t)blockIdx.x * 256 + threadIdx.x) * 4;
    if (i >= TN) return;
    int d = (int)(i & 63);
    int srow = (int)((i >> 6) & (S_ - 1));
    int bh = (int)(i >> 17);                 // 64*2048 = 2^17
    float l = Lp[(size_t)bh * S_ + srow] + Lp[((size_t)(B_ * H_) + bh) * S_ + srow];
    float rl = 1.0f / l;
    f32x4 o0 = *(const f32x4*)&Op[((size_t)bh * S_ + srow) * D_ + d];
    f32x4 o1 = *(const f32x4*)&Op[(((size_t)(B_ * H_) + bh) * S_ + srow) * D_ + d];
    int b = bh >> 4, h = bh & 15;
    u16x4 v;
#pragma unroll
    for (int e = 0; e < 4; e++) v[e] = f2bf((o0[e] + o1[e]) * rl);
    *(u16x4*)&ctx[((size_t)b * S_ + srow) * E_ + h * 64 + d] = v;
}

// ---------------- Kernel 3: output projection (bf16, g2l16) -----------------
__global__ __launch_bounds__(256, 4) void out_bf(
    const unsigned short* __restrict__ Cx, const unsigned short* __restrict__ Wob,
    const float* __restrict__ bo, float* __restrict__ out)
{
    __shared__ unsigned short As[128 * 32];
    __shared__ unsigned short Bs[64 * 32];
    const int t = threadIdx.x;
    const int w = t >> 6, lane = t & 63, quad = lane >> 4, l16 = lane & 15;
    const int m0 = blockIdx.y * 128, n0 = blockIdx.x * 64;
    const int wr = w * 32;
    const int r4 = t >> 2, c8 = (t & 3) * 8;
    const unsigned short* Ag = Cx  + (size_t)(m0 + r4) * E_ + c8;
    const unsigned short* Bg = Wob + (size_t)(n0 + r4) * E_ + c8;

    f32x4 zero = {0.f, 0.f, 0.f, 0.f};
    f32x4 acc[2][4];
#pragma unroll
    for (int i = 0; i < 2; i++)
#pragma unroll
        for (int j = 0; j < 4; j++) acc[i][j] = zero;

    for (int kt = 0; kt < E_; kt += 32) {
        __syncthreads();
        g2l16(Ag + kt,           &As[t * 8]);
        g2l16(Ag + 64 * E_ + kt, &As[t * 8 + 2048]);
        g2l16(Bg + kt,           &Bs[t * 8]);
        __syncthreads();
        bf16x8 af[2], bfr[4];
#pragma unroll
        for (int i = 0; i < 2; i++)
            af[i] = *(const bf16x8*)&As[(wr + i * 16 + l16) * 32 + quad * 8];
#pragma unroll
        for (int j = 0; j < 4; j++)
            bfr[j] = *(const bf16x8*)&Bs[(j * 16 + l16) * 32 + quad * 8];
#pragma unroll
        for (int i = 0; i < 2; i++)
#pragma unroll
            for (int j = 0; j < 4; j++)
                acc[i][j] = mfma16(af[i], bfr[j], acc[i][j]);
    }

#pragma unroll
    for (int j = 0; j < 4; j++) {
        int n = n0 + j * 16 + l16;
        float bvv = bo[n];
#pragma unroll
        for (int i = 0; i < 2; i++) {
            int mrow = m0 + wr + i * 16 + quad * 4;
#pragma unroll
            for (int r = 0; r < 4; r++)
                out[(size_t)(mrow + r) * E_ + n] = acc[i][j][r] + bvv;
        }
    }
}

// ================= f32 fallback (ws < 5*TN*2) ================================
__global__ __launch_bounds__(256, 3) void qkv_rope_f32(
    const float* __restrict__ X,
    const float* __restrict__ Wq, const float* __restrict__ Wk,
    const float* __restrict__ Wv,
    const float* __restrict__ bq, const float* __restrict__ bk,
    const float* __restrict__ bv,
    unsigned short* __restrict__ Qo, unsigned short* __restrict__ Ko,
    unsigned short* __restrict__ Vo)
{
    __shared__ __align__(16) unsigned char lds_raw[128 * 132 * 2];
    unsigned short* As = (unsigned short*)lds_raw;
    unsigned short* Bs = (unsigned short*)(lds_raw + 8192);
    unsigned short* Cs = (unsigned short*)lds_raw;

    const int t = threadIdx.x;
    const int w = t >> 6, lane = t & 63, quad = lane >> 4, l16 = lane & 15;
    const int wr = (w >> 1) * 64, wc = (w & 1) * 64;
    const int n0 = blockIdx.x * 128, m0 = blockIdx.y * 128;
    const int z = blockIdx.z;
    const float* W    = (z == 0) ? Wq : (z == 1) ? Wk : Wv;
    const float* bias = (z == 0) ? bq : (z == 1) ? bk : bv;

    const int r4 = t >> 2, c8 = (t & 3) * 8;
    const int st = r4 * PT + c8;
    const float* Ag = X + (size_t)(m0 + r4) * E_ + c8;
    const float* Bg = W + (size_t)(n0 + r4) * E_ + c8;

    f32x4 zero = {0.f, 0.f, 0.f, 0.f};
    f32x4 acc[4][4];
#pragma unroll
    for (int i = 0; i < 4; i++)
#pragma unroll
        for (int j = 0; j < 4; j++) acc[i][j] = zero;

    for (int kt = 0; kt < E_; kt += 32) {
        bf16x8 a0 = cvt8(Ag + kt);
        bf16x8 a1 = cvt8(Ag + 64 * E_ + kt);
        bf16x8 b0 = cvt8(Bg + kt);
        bf16x8 b1 = cvt8(Bg + 64 * E_ + kt);
        __syncthreads();
        *(bf16x8*)&As[st]           = a0;
        *(bf16x8*)&As[st + 64 * PT] = a1;
        *(bf16x8*)&Bs[st]           = b0;
        *(bf16x8*)&Bs[st + 64 * PT] = b1;
        __syncthreads();
        bf16x8 af[4], bfr[4];
#pragma unroll
        for (int i = 0; i < 4; i++)
            af[i] = *(const bf16x8*)&As[(wr + i * 16 + l16) * PT + quad * 8];
#pragma unroll
        for (int j = 0; j < 4; j++)
            bfr[j] = *(const bf16x8*)&Bs[(wc + j * 16 + l16) * PT + quad * 8];
#pragma unroll
        for (int i = 0; i < 4; i++)
#pragma unroll
            for (int j = 0; j < 4; j++)
                acc[i][j] = mfma16(af[i], bfr[j], acc[i][j]);
    }

    __syncthreads();
    const int seg = quad;
    if (z < 2) {
        const float C = -0.41524101186091903f;
        const float INV2PI = 0.15915494309189535f;
#pragma unroll
        for (int j = 0; j < 4; j++) {
            int n_local = wc + j * 16 + l16;
            int n = n0 + n_local;
            int d = n & 63, f = d >> 1;
            float inv_rev = exp2f(C * (float)f) * INV2PI;
            float bvv = bias[n];
            float sgn = (d & 1) ? 1.f : -1.f;
#pragma unroll
            for (int i = 0; i < 4; i++) {
                int mb = wr + i * 16 + quad * 4;
#pragma unroll
                for (int r = 0; r < 4; r++) {
                    int m = m0 + mb + r;
                    int s = m & (S_ - 1);
                    float val = acc[i][j][r] + bvv;
                    float oth = __shfl_xor(val, 1);
                    float rev = (float)s * inv_rev;
                    float fr = rev - rintf(rev);
                    float sn = __builtin_amdgcn_sinf(fr);
                    float cs = __builtin_amdgcn_cosf(fr);
                    Cs[(mb + r) * 132 + n_local] = f2bf(val * cs + sgn * oth * sn);
                }
            }
        }
        __syncthreads();
        unsigned short* Out = (z == 0) ? Qo : Ko;
        const int btok = m0 >> 11;
        const int half = seg & 1;
#pragma unroll
        for (int it = 0; it < 16; it++) {
            int m_local = it * 8 + w * 2 + (seg >> 1);
            int s = (m0 + m_local) & (S_ - 1);
            int h = (n0 + half * 64) >> 6;
            u16x4 v = *(const u16x4*)&Cs[m_local * 132 + half * 64 + l16 * 4];
            *(u16x4*)&Out[(((size_t)btok * H_ + h) * S_ + s) * D_ + l16 * 4] = v;
        }
    } else {
#pragma unroll
        for (int j = 0; j < 4; j++) {
            int n_local = wc + j * 16 + l16;
            float bvv = bias[n0 + n_local];
#pragma unroll
            for (int i = 0; i < 4; i++) {
                int mb = wr + i * 16 + quad * 4;
#pragma unroll
                for (int r = 0; r < 4; r++)
                    Cs[n_local * 132 + mb + r] = f2bf(acc[i][j][r] + bvv);
            }
        }
        __syncthreads();
        const int btok = m0 >> 11;
        const int s0 = m0 & (S_ - 1);
        const int half = seg & 1;
#pragma unroll
        for (int it = 0; it < 16; it++) {
            int n_local = it * 8 + w * 2 + (seg >> 1);
            int n = n0 + n_local;
            int h = n >> 6, d = n & 63;
            u16x4 v = *(const u16x4*)&Cs[n_local * 132 + half * 64 + l16 * 4];
            *(u16x4*)&Vo[(((size_t)btok * H_ + h) * D_ + d) * S_ + s0 + half * 64 + l16 * 4] = v;
        }
    }
}

__global__ __launch_bounds__(256, 2) void out_f32(
    const unsigned short* __restrict__ Cx, const float* __restrict__ Wo,
    const float* __restrict__ bo, float* __restrict__ out)
{
    __shared__ unsigned short As[128 * PT];
    __shared__ unsigned short Bs[64 * PT];
    const int t = threadIdx.x;
    const int w = t >> 6, lane = t & 63, quad = lane >> 4, l16 = lane & 15;
    const int m0 = blockIdx.y * 128, n0 = blockIdx.x * 64;
    const int wr = w * 32;
    const int r4 = t >> 2, c8 = (t & 3) * 8;
    const int st = r4 * PT + c8;
    const unsigned short* Ag = Cx + (size_t)(m0 + r4) * E_ + c8;
    const float*          Bg = Wo + (size_t)(n0 + (r4 & 63)) * E_ + c8;

    f32x4 zero = {0.f, 0.f, 0.f, 0.f};
    f32x4 acc[2][4];
#pragma unroll
    for (int i = 0; i < 2; i++)
#pragma unroll
        for (int j = 0; j < 4; j++) acc[i][j] = zero;

    for (int kt = 0; kt < E_; kt += 32) {
        bf16x8 a0 = *(const bf16x8*)(Ag + kt);
        bf16x8 a1 = *(const bf16x8*)(Ag + 64 * E_ + kt);
        bf16x8 b0 = cvt8(Bg + kt);
        __syncthreads();
        *(bf16x8*)&As[st]           = a0;
        *(bf16x8*)&As[st + 64 * PT] = a1;
        *(bf16x8*)&Bs[st]           = b0;
        __syncthreads();
        bf16x8 af[2], bfr[4];
#pragma unroll
        for (int i = 0; i < 2; i++)
            af[i] = *(const bf16x8*)&As[(wr + i * 16 + l16) * PT + quad * 8];
#pragma unroll
        for (int j = 0; j < 4; j++)
            bfr[j] = *(const bf16x8*)&Bs[(j * 16 + l16) * PT + quad * 8];
#pragma unroll
        for (int i = 0; i < 2; i++)
#pragma unroll
            for (int j = 0; j < 4; j++)
                acc[i][j] = mfma16(af[i], bfr[j], acc[i][j]);
    }

#pragma unroll
    for (int j = 0; j < 4; j++) {
        int n = n0 + j * 16 + l16;
        float bvv = bo[n];
#pragma unroll
        for (int i = 0; i < 2; i++) {
            int mrow = m0 + wr + i * 16 + quad * 4;
#pragma unroll
            for (int r = 0; r < 4; r++)
                out[(size_t)(mrow + r) * E_ + n] = acc[i][j][r] + bvv;
        }
    }
}

extern "C" void kernel_launch(void* const* d_in, const int* in_sizes, int n_in,
                              void* d_out, int out_size, void* d_ws, size_t ws_size,
                              hipStream_t stream) {
    const float* X  = (const float*)d_in[0];
    const float* Wq = (const float*)d_in[1];
    const float* bq = (const float*)d_in[2];
    const float* Wk = (const float*)d_in[3];
    const float* bk = (const float*)d_in[4];
    const float* Wv = (const float*)d_in[5];
    const float* bv = (const float*)d_in[6];
    const float* Wo = (const float*)d_in[7];
    const float* bo = (const float*)d_in[8];
    float* outp = (float*)d_out;

    const size_t TN = (size_t)B_ * H_ * S_ * D_;  // 4.19M elements
    const size_t need_f32   = 4 * TN * sizeof(unsigned short);
    const size_t need_bf    = 5 * TN * sizeof(unsigned short);
    const size_t need_split = need_bf + 2 * TN * sizeof(float)
                            + 2 * (size_t)(B_ * H_ * S_) * sizeof(float);
    if (ws_size < need_f32) return;

    unsigned short* Qb = (unsigned short*)d_ws;
    unsigned short* Kb = Qb + TN;
    unsigned short* Vb = Kb + TN;

    if (ws_size >= need_bf) {
        unsigned short* Xb = Vb + TN;   // aliased by Cx after qkv (stream-ordered)
        unsigned short* Wb = Xb + TN;
        unsigned short* Cx = Xb;

        cvt_kernel<<<dim3(2048, 5), 256, 0, stream>>>(X, Wq, Wk, Wv, Wo, Xb, Wb);
        qkv_rope_bf<<<dim3(E_ / 128, M_ / 128, 3), 256, 0, stream>>>(
            Xb, Wb, bq, bk, bv, Qb, Kb, Vb);

        if (ws_size >= need_split) {
            float* Op = (float*)(Wb + 4 * (size_t)(E_ * E_));
            float* Lp = Op + 2 * TN;
            attn_split<<<dim3(S_ / 128, B_ * H_, 2), 512, 0, stream>>>(
                Qb, Kb, Vb, Op, Lp);
            combine_kernel<<<dim3((int)(TN / 1024)), 256, 0, stream>>>(Op, Lp, Cx);
        } else {
            attn_direct<<<dim3(S_ / 128, B_ * H_), 512, 0, stream>>>(Qb, Kb, Vb, Cx);
        }
        out_bf<<<dim3(E_ / 64, M_ / 128), 256, 0, stream>>>(
            Cx, Wb + 3 * (size_t)(E_ * E_), bo, outp);
    } else {
        unsigned short* Cx = Vb + TN;
        qkv_rope_f32<<<dim3(E_ / 128, M_ / 128, 3), 256, 0, stream>>>(
            X, Wq, Wk, Wv, bq, bk, bv, Qb, Kb, Vb);
        attn_direct<<<dim3(S_ / 128, B_ * H_), 512, 0, stream>>>(Qb, Kb, Vb, Cx);
        out_f32<<<dim3(E_ / 64, M_ / 128), 256, 0, stream>>>(Cx, Wo, bo, outp);
    }
}

// Round 14
// 203.678 us; speedup vs baseline: 1.0479x; 1.0479x over previous
//
#include <hip/hip_runtime.h>
#include <hip/hip_bf16.h>
#include <math.h>

#define B_ 2
#define S_ 2048
#define E_ 1024
#define H_ 16
#define D_ 64
#define M_ (B_*S_)
#define PT 32

typedef short bf16x8 __attribute__((ext_vector_type(8)));
typedef float f32x4 __attribute__((ext_vector_type(4)));
typedef unsigned short u16x4 __attribute__((ext_vector_type(4)));

__device__ __forceinline__ unsigned short f2bf(float f) {
    unsigned int u = __builtin_bit_cast(unsigned int, f);
    u += 0x7FFFu + ((u >> 16) & 1u);
    return (unsigned short)(u >> 16);
}
// packed f32x2 -> bf16x2 (v_cvt_pk_bf16_f32); memcpy avoids bit_cast trap
__device__ __forceinline__ unsigned int pk2bf(float a, float b) {
    __hip_bfloat162 h = __float22bfloat162_rn(make_float2(a, b));
    unsigned int u;
    __builtin_memcpy(&u, &h, 4);
    return u;
}
__device__ __forceinline__ f32x4 mfma16(bf16x8 a, bf16x8 b, f32x4 c) {
    return __builtin_amdgcn_mfma_f32_16x16x32_bf16(a, b, c, 0, 0, 0);
}
__device__ __forceinline__ bf16x8 cvt8(const float* p) {
    f32x4 lo = *(const f32x4*)p;
    f32x4 hi = *(const f32x4*)(p + 4);
    unsigned int pk[4];
    pk[0] = pk2bf(lo[0], lo[1]);
    pk[1] = pk2bf(lo[2], lo[3]);
    pk[2] = pk2bf(hi[0], hi[1]);
    pk[3] = pk2bf(hi[2], hi[3]);
    bf16x8 r;
    __builtin_memcpy(&r, pk, 16);
    return r;
}
__device__ __forceinline__ void g2l16(const unsigned short* g, unsigned short* l) {
    __builtin_amdgcn_global_load_lds(
        (const __attribute__((address_space(1))) unsigned int*)(const void*)g,
        (__attribute__((address_space(3))) unsigned int*)(void*)l,
        16, 0, 0);
}

// ---------------- Kernel 0: f32 -> bf16 conversion (X + 4 weights) ----------
__global__ __launch_bounds__(256) void cvt_kernel(
    const float* __restrict__ X,  const float* __restrict__ Wq,
    const float* __restrict__ Wk, const float* __restrict__ Wv,
    const float* __restrict__ Wo,
    unsigned short* __restrict__ Xb, unsigned short* __restrict__ Wb)
{
    const int y = blockIdx.y;
    const float* src = (y == 0) ? X : (y == 1) ? Wq : (y == 2) ? Wk : (y == 3) ? Wv : Wo;
    unsigned short* dst = (y == 0) ? Xb : Wb + (size_t)(y - 1) * (E_ * E_);
    const size_t n = (y == 0) ? (size_t)M_ * E_ : (size_t)E_ * E_;
    size_t i = ((size_t)blockIdx.x * 256 + threadIdx.x) * 8;
    if (i < n) *(bf16x8*)(dst + i) = cvt8(src + i);
}

// ---------------- Kernel 1: QKV proj + RoPE (bf16, g2l16) -------------------
__global__ __launch_bounds__(256, 4) void qkv_rope_bf(
    const unsigned short* __restrict__ Xb, const unsigned short* __restrict__ Wb,
    const float* __restrict__ bq, const float* __restrict__ bk,
    const float* __restrict__ bv,
    unsigned short* __restrict__ Qo, unsigned short* __restrict__ Ko,
    unsigned short* __restrict__ Vo)
{
    __shared__ __align__(16) unsigned char lds_raw[128 * 132 * 2];
    unsigned short* As = (unsigned short*)lds_raw;
    unsigned short* Bs = (unsigned short*)(lds_raw + 8192);
    unsigned short* Cs = (unsigned short*)lds_raw;

    const int t = threadIdx.x;
    const int w = t >> 6, lane = t & 63, quad = lane >> 4, l16 = lane & 15;
    const int wr = (w >> 1) * 64, wc = (w & 1) * 64;
    const int n0 = blockIdx.x * 128, m0 = blockIdx.y * 128;
    const int z = blockIdx.z;
    const unsigned short* W = Wb + (size_t)z * (E_ * E_);
    const float* bias = (z == 0) ? bq : (z == 1) ? bk : bv;

    const int r4 = t >> 2, c8 = (t & 3) * 8;
    const unsigned short* Ag = Xb + (size_t)(m0 + r4) * E_ + c8;
    const unsigned short* Bg = W  + (size_t)(n0 + r4) * E_ + c8;

    f32x4 zero = {0.f, 0.f, 0.f, 0.f};
    f32x4 acc[4][4];
#pragma unroll
    for (int i = 0; i < 4; i++)
#pragma unroll
        for (int j = 0; j < 4; j++) acc[i][j] = zero;

    for (int kt = 0; kt < E_; kt += 32) {
        __syncthreads();
        g2l16(Ag + kt,           &As[t * 8]);
        g2l16(Ag + 64 * E_ + kt, &As[t * 8 + 2048]);
        g2l16(Bg + kt,           &Bs[t * 8]);
        g2l16(Bg + 64 * E_ + kt, &Bs[t * 8 + 2048]);
        __syncthreads();
        bf16x8 af[4], bfr[4];
#pragma unroll
        for (int i = 0; i < 4; i++)
            af[i] = *(const bf16x8*)&As[(wr + i * 16 + l16) * 32 + quad * 8];
#pragma unroll
        for (int j = 0; j < 4; j++)
            bfr[j] = *(const bf16x8*)&Bs[(wc + j * 16 + l16) * 32 + quad * 8];
#pragma unroll
        for (int i = 0; i < 4; i++)
#pragma unroll
            for (int j = 0; j < 4; j++)
                acc[i][j] = mfma16(af[i], bfr[j], acc[i][j]);
    }

    __syncthreads();
    const int seg = quad;
    if (z < 2) {
        const float C = -0.41524101186091903f;
        const float INV2PI = 0.15915494309189535f;
#pragma unroll
        for (int j = 0; j < 4; j++) {
            int n_local = wc + j * 16 + l16;
            int n = n0 + n_local;
            int d = n & 63, f = d >> 1;
            float inv_rev = exp2f(C * (float)f) * INV2PI;
            float bvv = bias[n];
            float sgn = (d & 1) ? 1.f : -1.f;
#pragma unroll
            for (int i = 0; i < 4; i++) {
                int mb = wr + i * 16 + quad * 4;
#pragma unroll
                for (int r = 0; r < 4; r++) {
                    int m = m0 + mb + r;
                    int s = m & (S_ - 1);
                    float val = acc[i][j][r] + bvv;
                    float oth = __shfl_xor(val, 1);
                    float rev = (float)s * inv_rev;
                    float fr = rev - rintf(rev);
                    float sn = __builtin_amdgcn_sinf(fr);
                    float cs = __builtin_amdgcn_cosf(fr);
                    Cs[(mb + r) * 132 + n_local] = f2bf(val * cs + sgn * oth * sn);
                }
            }
        }
        __syncthreads();
        unsigned short* Out = (z == 0) ? Qo : Ko;
        const int btok = m0 >> 11;
        const int half = seg & 1;
#pragma unroll
        for (int it = 0; it < 16; it++) {
            int m_local = it * 8 + w * 2 + (seg >> 1);
            int s = (m0 + m_local) & (S_ - 1);
            int h = (n0 + half * 64) >> 6;
            u16x4 v = *(const u16x4*)&Cs[m_local * 132 + half * 64 + l16 * 4];
            *(u16x4*)&Out[(((size_t)btok * H_ + h) * S_ + s) * D_ + l16 * 4] = v;
        }
    } else {
#pragma unroll
        for (int j = 0; j < 4; j++) {
            int n_local = wc + j * 16 + l16;
            float bvv = bias[n0 + n_local];
#pragma unroll
            for (int i = 0; i < 4; i++) {
                int mb = wr + i * 16 + quad * 4;
#pragma unroll
                for (int r = 0; r < 4; r++)
                    Cs[n_local * 132 + mb + r] = f2bf(acc[i][j][r] + bvv);
            }
        }
        __syncthreads();
        const int btok = m0 >> 11;
        const int s0 = m0 & (S_ - 1);
        const int half = seg & 1;
#pragma unroll
        for (int it = 0; it < 16; it++) {
            int n_local = it * 8 + w * 2 + (seg >> 1);
            int n = n0 + n_local;
            int h = n >> 6, d = n & 63;
            u16x4 v = *(const u16x4*)&Cs[n_local * 132 + half * 64 + l16 * 4];
            *(u16x4*)&Vo[(((size_t)btok * H_ + h) * D_ + d) * S_ + s0 + half * 64 + l16 * 4] = v;
        }
    }
}

// ---------------- Kernel 2: attention, 512 thr, double-buffered K/V ---------
__global__ __launch_bounds__(512, 3) void attn_direct(
    const unsigned short* __restrict__ Q, const unsigned short* __restrict__ K,
    const unsigned short* __restrict__ Vt, unsigned short* __restrict__ ctx)
{
    __shared__ unsigned short KsD[2][64 * 64];   // [buf][key*32 halves packed]
    __shared__ unsigned short VsD[2][64 * 64];
    __shared__ unsigned short Ps[8][16 * 72];
    const int t = threadIdx.x;
    const int w = t >> 6, lane = t & 63, quad = lane >> 4, l16 = lane & 15;
    const int bh = blockIdx.y;
    const int q0 = blockIdx.x * 128 + w * 16;

    const unsigned short* Qg = Q + ((size_t)bh * S_ + q0) * D_;
    bf16x8 qf[2];
#pragma unroll
    for (int ks = 0; ks < 2; ks++)
        qf[ks] = *(const bf16x8*)(Qg + (size_t)l16 * 64 + ks * 32 + quad * 8);

    bf16x8 ones;
#pragma unroll
    for (int e = 0; e < 8; e++) ones[e] = (short)0x3F80;

    f32x4 zero = {0.f, 0.f, 0.f, 0.f};
    f32x4 acc_o[4];
    f32x4 acc_l = zero;
#pragma unroll
    for (int j = 0; j < 4; j++) acc_o[j] = zero;

    // staging map: 512 threads x 16B each cover the 64x64 K (and V) tile
    const int tt = t & 255, ksel = t >> 8;
    const int sr = tt >> 2, sc = (tt & 3) * 8;
    const unsigned short* KgL = K  + (size_t)bh * S_ * D_ + (size_t)sr * 64 + ksel * 32 + sc;
    const unsigned short* VgL = Vt + (size_t)bh * D_ * S_ + (size_t)sr * S_ + ksel * 32 + sc;

    const float SCL = 0.18033688011f;  // log2(e)/8

    // prologue: stage tile 0 into buf 0
    g2l16(KgL, &KsD[0][t * 8]);
    g2l16(VgL, &VsD[0][t * 8]);
    __syncthreads();

    int p = 0;
    for (int kt = 0; kt < S_; kt += 64) {
        // prefetch next tile into the other buffer (overlaps compute below)
        if (kt + 64 < S_) {
            g2l16(KgL + (size_t)(kt + 64) * 64, &KsD[1 - p][t * 8]);
            g2l16(VgL + (kt + 64),              &VsD[1 - p][t * 8]);
        }

        f32x4 sc4[4];
#pragma unroll
        for (int j = 0; j < 4; j++) sc4[j] = zero;
#pragma unroll
        for (int ks = 0; ks < 2; ks++) {
#pragma unroll
            for (int j = 0; j < 4; j++) {
                bf16x8 kf = *(const bf16x8*)&KsD[p][ks * 2048 + (j * 16 + l16) * 32 + quad * 8];
                sc4[j] = mfma16(qf[ks], kf, sc4[j]);
            }
        }
        // exp + packed bf16 cvt (v_cvt_pk_bf16_f32), P -> per-wave LDS buffer
#pragma unroll
        for (int j = 0; j < 4; j++)
#pragma unroll
            for (int r = 0; r < 4; r += 2) {
                float pa = __builtin_amdgcn_exp2f(sc4[j][r]     * SCL);
                float pb = __builtin_amdgcn_exp2f(sc4[j][r + 1] * SCL);
                unsigned int u = pk2bf(pa, pb);
                Ps[w][(quad * 4 + r)     * 72 + j * 16 + l16] = (unsigned short)u;
                Ps[w][(quad * 4 + r + 1) * 72 + j * 16 + l16] = (unsigned short)(u >> 16);
            }
#pragma unroll
        for (int ks = 0; ks < 2; ks++) {
            bf16x8 pf = *(const bf16x8*)&Ps[w][l16 * 72 + ks * 32 + quad * 8];
#pragma unroll
            for (int jd = 0; jd < 4; jd++) {
                bf16x8 vf = *(const bf16x8*)&VsD[p][ks * 2048 + (jd * 16 + l16) * 32 + quad * 8];
                acc_o[jd] = mfma16(pf, vf, acc_o[jd]);
            }
            acc_l = mfma16(pf, ones, acc_l);
        }

        __syncthreads();   // drains prefetch (vmcnt) + guards buf reuse; 1 barrier/iter
        p ^= 1;
    }

    const int b = bh >> 4, h = bh & 15;
    f32x4 rl;
#pragma unroll
    for (int r = 0; r < 4; r++) rl[r] = 1.0f / acc_l[r];
#pragma unroll
    for (int jd = 0; jd < 4; jd++)
#pragma unroll
        for (int r = 0; r < 4; r++) {
            int qrow = q0 + quad * 4 + r;
            int col = h * 64 + jd * 16 + l16;
            ctx[((size_t)b * S_ + qrow) * E_ + col] = f2bf(acc_o[jd][r] * rl[r]);
        }
}

// ---------------- Kernel 3: output projection (bf16, g2l16) -----------------
__global__ __launch_bounds__(256, 4) void out_bf(
    const unsigned short* __restrict__ Cx, const unsigned short* __restrict__ Wob,
    const float* __restrict__ bo, float* __restrict__ out)
{
    __shared__ unsigned short As[128 * 32];
    __shared__ unsigned short Bs[64 * 32];
    const int t = threadIdx.x;
    const int w = t >> 6, lane = t & 63, quad = lane >> 4, l16 = lane & 15;
    const int m0 = blockIdx.y * 128, n0 = blockIdx.x * 64;
    const int wr = w * 32;
    const int r4 = t >> 2, c8 = (t & 3) * 8;
    const unsigned short* Ag = Cx  + (size_t)(m0 + r4) * E_ + c8;
    const unsigned short* Bg = Wob + (size_t)(n0 + r4) * E_ + c8;

    f32x4 zero = {0.f, 0.f, 0.f, 0.f};
    f32x4 acc[2][4];
#pragma unroll
    for (int i = 0; i < 2; i++)
#pragma unroll
        for (int j = 0; j < 4; j++) acc[i][j] = zero;

    for (int kt = 0; kt < E_; kt += 32) {
        __syncthreads();
        g2l16(Ag + kt,           &As[t * 8]);
        g2l16(Ag + 64 * E_ + kt, &As[t * 8 + 2048]);
        g2l16(Bg + kt,           &Bs[t * 8]);
        __syncthreads();
        bf16x8 af[2], bfr[4];
#pragma unroll
        for (int i = 0; i < 2; i++)
            af[i] = *(const bf16x8*)&As[(wr + i * 16 + l16) * 32 + quad * 8];
#pragma unroll
        for (int j = 0; j < 4; j++)
            bfr[j] = *(const bf16x8*)&Bs[(j * 16 + l16) * 32 + quad * 8];
#pragma unroll
        for (int i = 0; i < 2; i++)
#pragma unroll
            for (int j = 0; j < 4; j++)
                acc[i][j] = mfma16(af[i], bfr[j], acc[i][j]);
    }

#pragma unroll
    for (int j = 0; j < 4; j++) {
        int n = n0 + j * 16 + l16;
        float bvv = bo[n];
#pragma unroll
        for (int i = 0; i < 2; i++) {
            int mrow = m0 + wr + i * 16 + quad * 4;
#pragma unroll
            for (int r = 0; r < 4; r++)
                out[(size_t)(mrow + r) * E_ + n] = acc[i][j][r] + bvv;
        }
    }
}

// ================= f32 fallback (ws < 5*TN*2) ================================
__global__ __launch_bounds__(256, 3) void qkv_rope_f32(
    const float* __restrict__ X,
    const float* __restrict__ Wq, const float* __restrict__ Wk,
    const float* __restrict__ Wv,
    const float* __restrict__ bq, const float* __restrict__ bk,
    const float* __restrict__ bv,
    unsigned short* __restrict__ Qo, unsigned short* __restrict__ Ko,
    unsigned short* __restrict__ Vo)
{
    __shared__ __align__(16) unsigned char lds_raw[128 * 132 * 2];
    unsigned short* As = (unsigned short*)lds_raw;
    unsigned short* Bs = (unsigned short*)(lds_raw + 8192);
    unsigned short* Cs = (unsigned short*)lds_raw;

    const int t = threadIdx.x;
    const int w = t >> 6, lane = t & 63, quad = lane >> 4, l16 = lane & 15;
    const int wr = (w >> 1) * 64, wc = (w & 1) * 64;
    const int n0 = blockIdx.x * 128, m0 = blockIdx.y * 128;
    const int z = blockIdx.z;
    const float* W    = (z == 0) ? Wq : (z == 1) ? Wk : Wv;
    const float* bias = (z == 0) ? bq : (z == 1) ? bk : bv;

    const int r4 = t >> 2, c8 = (t & 3) * 8;
    const int st = r4 * PT + c8;
    const float* Ag = X + (size_t)(m0 + r4) * E_ + c8;
    const float* Bg = W + (size_t)(n0 + r4) * E_ + c8;

    f32x4 zero = {0.f, 0.f, 0.f, 0.f};
    f32x4 acc[4][4];
#pragma unroll
    for (int i = 0; i < 4; i++)
#pragma unroll
        for (int j = 0; j < 4; j++) acc[i][j] = zero;

    for (int kt = 0; kt < E_; kt += 32) {
        bf16x8 a0 = cvt8(Ag + kt);
        bf16x8 a1 = cvt8(Ag + 64 * E_ + kt);
        bf16x8 b0 = cvt8(Bg + kt);
        bf16x8 b1 = cvt8(Bg + 64 * E_ + kt);
        __syncthreads();
        *(bf16x8*)&As[st]           = a0;
        *(bf16x8*)&As[st + 64 * PT] = a1;
        *(bf16x8*)&Bs[st]           = b0;
        *(bf16x8*)&Bs[st + 64 * PT] = b1;
        __syncthreads();
        bf16x8 af[4], bfr[4];
#pragma unroll
        for (int i = 0; i < 4; i++)
            af[i] = *(const bf16x8*)&As[(wr + i * 16 + l16) * PT + quad * 8];
#pragma unroll
        for (int j = 0; j < 4; j++)
            bfr[j] = *(const bf16x8*)&Bs[(wc + j * 16 + l16) * PT + quad * 8];
#pragma unroll
        for (int i = 0; i < 4; i++)
#pragma unroll
            for (int j = 0; j < 4; j++)
                acc[i][j] = mfma16(af[i], bfr[j], acc[i][j]);
    }

    __syncthreads();
    const int seg = quad;
    if (z < 2) {
        const float C = -0.41524101186091903f;
        const float INV2PI = 0.15915494309189535f;
#pragma unroll
        for (int j = 0; j < 4; j++) {
            int n_local = wc + j * 16 + l16;
            int n = n0 + n_local;
            int d = n & 63, f = d >> 1;
            float inv_rev = exp2f(C * (float)f) * INV2PI;
            float bvv = bias[n];
            float sgn = (d & 1) ? 1.f : -1.f;
#pragma unroll
            for (int i = 0; i < 4; i++) {
                int mb = wr + i * 16 + quad * 4;
#pragma unroll
                for (int r = 0; r < 4; r++) {
                    int m = m0 + mb + r;
                    int s = m & (S_ - 1);
                    float val = acc[i][j][r] + bvv;
                    float oth = __shfl_xor(val, 1);
                    float rev = (float)s * inv_rev;
                    float fr = rev - rintf(rev);
                    float sn = __builtin_amdgcn_sinf(fr);
                    float cs = __builtin_amdgcn_cosf(fr);
                    Cs[(mb + r) * 132 + n_local] = f2bf(val * cs + sgn * oth * sn);
                }
            }
        }
        __syncthreads();
        unsigned short* Out = (z == 0) ? Qo : Ko;
        const int btok = m0 >> 11;
        const int half = seg & 1;
#pragma unroll
        for (int it = 0; it < 16; it++) {
            int m_local = it * 8 + w * 2 + (seg >> 1);
            int s = (m0 + m_local) & (S_ - 1);
            int h = (n0 + half * 64) >> 6;
            u16x4 v = *(const u16x4*)&Cs[m_local * 132 + half * 64 + l16 * 4];
            *(u16x4*)&Out[(((size_t)btok * H_ + h) * S_ + s) * D_ + l16 * 4] = v;
        }
    } else {
#pragma unroll
        for (int j = 0; j < 4; j++) {
            int n_local = wc + j * 16 + l16;
            float bvv = bias[n0 + n_local];
#pragma unroll
            for (int i = 0; i < 4; i++) {
                int mb = wr + i * 16 + quad * 4;
#pragma unroll
                for (int r = 0; r < 4; r++)
                    Cs[n_local * 132 + mb + r] = f2bf(acc[i][j][r] + bvv);
            }
        }
        __syncthreads();
        const int btok = m0 >> 11;
        const int s0 = m0 & (S_ - 1);
        const int half = seg & 1;
#pragma unroll
        for (int it = 0; it < 16; it++) {
            int n_local = it * 8 + w * 2 + (seg >> 1);
            int n = n0 + n_local;
            int h = n >> 6, d = n & 63;
            u16x4 v = *(const u16x4*)&Cs[n_local * 132 + half * 64 + l16 * 4];
            *(u16x4*)&Vo[(((size_t)btok * H_ + h) * D_ + d) * S_ + s0 + half * 64 + l16 * 4] = v;
        }
    }
}

__global__ __launch_bounds__(256, 2) void out_f32(
    const unsigned short* __restrict__ Cx, const float* __restrict__ Wo,
    const float* __restrict__ bo, float* __restrict__ out)
{
    __shared__ unsigned short As[128 * PT];
    __shared__ unsigned short Bs[64 * PT];
    const int t = threadIdx.x;
    const int w = t >> 6, lane = t & 63, quad = lane >> 4, l16 = lane & 15;
    const int m0 = blockIdx.y * 128, n0 = blockIdx.x * 64;
    const int wr = w * 32;
    const int r4 = t >> 2, c8 = (t & 3) * 8;
    const int st = r4 * PT + c8;
    const unsigned short* Ag = Cx + (size_t)(m0 + r4) * E_ + c8;
    const float*          Bg = Wo + (size_t)(n0 + (r4 & 63)) * E_ + c8;

    f32x4 zero = {0.f, 0.f, 0.f, 0.f};
    f32x4 acc[2][4];
#pragma unroll
    for (int i = 0; i < 2; i++)
#pragma unroll
        for (int j = 0; j < 4; j++) acc[i][j] = zero;

    for (int kt = 0; kt < E_; kt += 32) {
        bf16x8 a0 = *(const bf16x8*)(Ag + kt);
        bf16x8 a1 = *(const bf16x8*)(Ag + 64 * E_ + kt);
        bf16x8 b0 = cvt8(Bg + kt);
        __syncthreads();
        *(bf16x8*)&As[st]           = a0;
        *(bf16x8*)&As[st + 64 * PT] = a1;
        *(bf16x8*)&Bs[st]           = b0;
        __syncthreads();
        bf16x8 af[2], bfr[4];
#pragma unroll
        for (int i = 0; i < 2; i++)
            af[i] = *(const bf16x8*)&As[(wr + i * 16 + l16) * PT + quad * 8];
#pragma unroll
        for (int j = 0; j < 4; j++)
            bfr[j] = *(const bf16x8*)&Bs[(j * 16 + l16) * PT + quad * 8];
#pragma unroll
        for (int i = 0; i < 2; i++)
#pragma unroll
            for (int j = 0; j < 4; j++)
                acc[i][j] = mfma16(af[i], bfr[j], acc[i][j]);
    }

#pragma unroll
    for (int j = 0; j < 4; j++) {
        int n = n0 + j * 16 + l16;
        float bvv = bo[n];
#pragma unroll
        for (int i = 0; i < 2; i++) {
            int mrow = m0 + wr + i * 16 + quad * 4;
#pragma unroll
            for (int r = 0; r < 4; r++)
                out[(size_t)(mrow + r) * E_ + n] = acc[i][j][r] + bvv;
        }
    }
}

extern "C" void kernel_launch(void* const* d_in, const int* in_sizes, int n_in,
                              void* d_out, int out_size, void* d_ws, size_t ws_size,
                              hipStream_t stream) {
    const float* X  = (const float*)d_in[0];
    const float* Wq = (const float*)d_in[1];
    const float* bq = (const float*)d_in[2];
    const float* Wk = (const float*)d_in[3];
    const float* bk = (const float*)d_in[4];
    const float* Wv = (const float*)d_in[5];
    const float* bv = (const float*)d_in[6];
    const float* Wo = (const float*)d_in[7];
    const float* bo = (const float*)d_in[8];
    float* outp = (float*)d_out;

    const size_t TN = (size_t)B_ * H_ * S_ * D_;
    const size_t need_f32 = 4 * TN * sizeof(unsigned short);
    const size_t need_bf  = 5 * TN * sizeof(unsigned short);
    if (ws_size < need_f32) return;

    unsigned short* Qb = (unsigned short*)d_ws;
    unsigned short* Kb = Qb + TN;
    unsigned short* Vb = Kb + TN;

    if (ws_size >= need_bf) {
        unsigned short* Xb = Vb + TN;   // aliased by Cx after qkv (stream-ordered)
        unsigned short* Wb = Xb + TN;
        unsigned short* Cx = Xb;

        cvt_kernel<<<dim3(2048, 5), 256, 0, stream>>>(X, Wq, Wk, Wv, Wo, Xb, Wb);
        qkv_rope_bf<<<dim3(E_ / 128, M_ / 128, 3), 256, 0, stream>>>(
            Xb, Wb, bq, bk, bv, Qb, Kb, Vb);
        attn_direct<<<dim3(S_ / 128, B_ * H_), 512, 0, stream>>>(Qb, Kb, Vb, Cx);
        out_bf<<<dim3(E_ / 64, M_ / 128), 256, 0, stream>>>(
            Cx, Wb + 3 * (size_t)(E_ * E_), bo, outp);
    } else {
        unsigned short* Cx = Vb + TN;
        qkv_rope_f32<<<dim3(E_ / 128, M_ / 128, 3), 256, 0, stream>>>(
            X, Wq, Wk, Wv, bq, bk, bv, Qb, Kb, Vb);
        attn_direct<<<dim3(S_ / 128, B_ * H_), 512, 0, stream>>>(Qb, Kb, Vb, Cx);
        out_f32<<<dim3(E_ / 64, M_ / 128), 256, 0, stream>>>(Cx, Wo, bo, outp);
    }
}

// Round 15
// 202.312 us; speedup vs baseline: 1.0550x; 1.0068x over previous
//
#include <hip/hip_runtime.h>
#include <hip/hip_bf16.h>
#include <math.h>

#define B_ 2
#define S_ 2048
#define E_ 1024
#define H_ 16
#define D_ 64
#define M_ (B_*S_)
#define PT 32

typedef short bf16x8 __attribute__((ext_vector_type(8)));
typedef float f32x4 __attribute__((ext_vector_type(4)));
typedef unsigned short u16x4 __attribute__((ext_vector_type(4)));

#define SCLQ 0.18033688011112042f  // log2(e)/8 folded into Q

__device__ __forceinline__ unsigned short f2bf(float f) {
    unsigned int u = __builtin_bit_cast(unsigned int, f);
    u += 0x7FFFu + ((u >> 16) & 1u);
    return (unsigned short)(u >> 16);
}
__device__ __forceinline__ unsigned int pk2bf(float a, float b) {
    __hip_bfloat162 h = __float22bfloat162_rn(make_float2(a, b));
    unsigned int u;
    __builtin_memcpy(&u, &h, 4);
    return u;
}
__device__ __forceinline__ f32x4 mfma16(bf16x8 a, bf16x8 b, f32x4 c) {
    return __builtin_amdgcn_mfma_f32_16x16x32_bf16(a, b, c, 0, 0, 0);
}
__device__ __forceinline__ bf16x8 cvt8(const float* p) {
    f32x4 lo = *(const f32x4*)p;
    f32x4 hi = *(const f32x4*)(p + 4);
    unsigned int pk[4];
    pk[0] = pk2bf(lo[0], lo[1]);
    pk[1] = pk2bf(lo[2], lo[3]);
    pk[2] = pk2bf(hi[0], hi[1]);
    pk[3] = pk2bf(hi[2], hi[3]);
    bf16x8 r;
    __builtin_memcpy(&r, pk, 16);
    return r;
}
__device__ __forceinline__ void g2l16(const unsigned short* g, unsigned short* l) {
    __builtin_amdgcn_global_load_lds(
        (const __attribute__((address_space(1))) unsigned int*)(const void*)g,
        (__attribute__((address_space(3))) unsigned int*)(void*)l,
        16, 0, 0);
}

// ---------------- Kernel 0: f32->bf16 conversion + RoPE tables --------------
__global__ __launch_bounds__(256) void cvt_kernel(
    const float* __restrict__ X,  const float* __restrict__ Wq,
    const float* __restrict__ Wk, const float* __restrict__ Wv,
    const float* __restrict__ Wo,
    unsigned short* __restrict__ Xb, unsigned short* __restrict__ Wb,
    float* __restrict__ tab)   // [cs 32*2048][sn 32*2048]
{
    const int y = blockIdx.y;
    if (y == 5) {
        // RoPE tables: tab[f*2048+s] = cos(angle), tab[65536 + f*2048+s] = sin
        unsigned int i = blockIdx.x * 256 + threadIdx.x;
        if (i < 32 * 2048) {
            int f = i >> 11, s = i & 2047;
            const float C = -0.41524101186091903f;     // -log2(10000)/32
            const float INV2PI = 0.15915494309189535f;
            float inv_rev = exp2f(C * (float)f) * INV2PI;
            float rev = (float)s * inv_rev;
            float fr = rev - rintf(rev);
            tab[i]           = __builtin_amdgcn_cosf(fr);
            tab[65536 + i]   = __builtin_amdgcn_sinf(fr);
        }
        return;
    }
    const float* src = (y == 0) ? X : (y == 1) ? Wq : (y == 2) ? Wk : (y == 3) ? Wv : Wo;
    unsigned short* dst = (y == 0) ? Xb : Wb + (size_t)(y - 1) * (E_ * E_);
    const size_t n = (y == 0) ? (size_t)M_ * E_ : (size_t)E_ * E_;
    size_t i = ((size_t)blockIdx.x * 256 + threadIdx.x) * 8;
    if (i < n) *(bf16x8*)(dst + i) = cvt8(src + i);
}

// ---------------- Kernel 1: QKV proj + RoPE (bf16, g2l16, table trig) -------
__global__ __launch_bounds__(256, 4) void qkv_rope_bf(
    const unsigned short* __restrict__ Xb, const unsigned short* __restrict__ Wb,
    const float* __restrict__ bq, const float* __restrict__ bk,
    const float* __restrict__ bv, const float* __restrict__ tab,
    unsigned short* __restrict__ Qo, unsigned short* __restrict__ Ko,
    unsigned short* __restrict__ Vo)
{
    __shared__ __align__(16) unsigned char lds_raw[128 * 132 * 2];
    unsigned short* As = (unsigned short*)lds_raw;
    unsigned short* Bs = (unsigned short*)(lds_raw + 8192);
    unsigned short* Cs = (unsigned short*)lds_raw;

    const int t = threadIdx.x;
    const int w = t >> 6, lane = t & 63, quad = lane >> 4, l16 = lane & 15;
    const int wr = (w >> 1) * 64, wc = (w & 1) * 64;
    const int n0 = blockIdx.x * 128, m0 = blockIdx.y * 128;
    const int z = blockIdx.z;
    const unsigned short* W = Wb + (size_t)z * (E_ * E_);
    const float* bias = (z == 0) ? bq : (z == 1) ? bk : bv;

    const int r4 = t >> 2, c8 = (t & 3) * 8;
    const unsigned short* Ag = Xb + (size_t)(m0 + r4) * E_ + c8;
    const unsigned short* Bg = W  + (size_t)(n0 + r4) * E_ + c8;

    f32x4 zero = {0.f, 0.f, 0.f, 0.f};
    f32x4 acc[4][4];
#pragma unroll
    for (int i = 0; i < 4; i++)
#pragma unroll
        for (int j = 0; j < 4; j++) acc[i][j] = zero;

    for (int kt = 0; kt < E_; kt += 32) {
        __syncthreads();
        g2l16(Ag + kt,           &As[t * 8]);
        g2l16(Ag + 64 * E_ + kt, &As[t * 8 + 2048]);
        g2l16(Bg + kt,           &Bs[t * 8]);
        g2l16(Bg + 64 * E_ + kt, &Bs[t * 8 + 2048]);
        __syncthreads();
        bf16x8 af[4], bfr[4];
#pragma unroll
        for (int i = 0; i < 4; i++)
            af[i] = *(const bf16x8*)&As[(wr + i * 16 + l16) * 32 + quad * 8];
#pragma unroll
        for (int j = 0; j < 4; j++)
            bfr[j] = *(const bf16x8*)&Bs[(wc + j * 16 + l16) * 32 + quad * 8];
#pragma unroll
        for (int i = 0; i < 4; i++)
#pragma unroll
            for (int j = 0; j < 4; j++)
                acc[i][j] = mfma16(af[i], bfr[j], acc[i][j]);
    }

    __syncthreads();
    const int seg = quad;
    if (z < 2) {
        const float qscale = (z == 0) ? SCLQ : 1.0f;
#pragma unroll
        for (int j = 0; j < 4; j++) {
            int n_local = wc + j * 16 + l16;
            int n = n0 + n_local;
            int d = n & 63, f = d >> 1;
            float bvv = bias[n];
            float sgn = (d & 1) ? 1.f : -1.f;
            const float* ct = tab + f * 2048;
            const float* st_ = tab + 65536 + f * 2048;
#pragma unroll
            for (int i = 0; i < 4; i++) {
                int mb = wr + i * 16 + quad * 4;
                int sb = (m0 + mb) & (S_ - 1);
                f32x4 cs4 = *(const f32x4*)&ct[sb];
                f32x4 sn4 = *(const f32x4*)&st_[sb];
#pragma unroll
                for (int r = 0; r < 4; r++) {
                    float val = acc[i][j][r] + bvv;
                    float oth = __shfl_xor(val, 1);
                    Cs[(mb + r) * 132 + n_local] =
                        f2bf((val * cs4[r] + sgn * oth * sn4[r]) * qscale);
                }
            }
        }
        __syncthreads();
        unsigned short* Out = (z == 0) ? Qo : Ko;
        const int btok = m0 >> 11;
        const int half = seg & 1;
#pragma unroll
        for (int it = 0; it < 16; it++) {
            int m_local = it * 8 + w * 2 + (seg >> 1);
            int s = (m0 + m_local) & (S_ - 1);
            int h = (n0 + half * 64) >> 6;
            u16x4 v = *(const u16x4*)&Cs[m_local * 132 + half * 64 + l16 * 4];
            *(u16x4*)&Out[(((size_t)btok * H_ + h) * S_ + s) * D_ + l16 * 4] = v;
        }
    } else {
#pragma unroll
        for (int j = 0; j < 4; j++) {
            int n_local = wc + j * 16 + l16;
            float bvv = bias[n0 + n_local];
#pragma unroll
            for (int i = 0; i < 4; i++) {
                int mb = wr + i * 16 + quad * 4;
#pragma unroll
                for (int r = 0; r < 4; r++)
                    Cs[n_local * 132 + mb + r] = f2bf(acc[i][j][r] + bvv);
            }
        }
        __syncthreads();
        const int btok = m0 >> 11;
        const int s0 = m0 & (S_ - 1);
        const int half = seg & 1;
#pragma unroll
        for (int it = 0; it < 16; it++) {
            int n_local = it * 8 + w * 2 + (seg >> 1);
            int n = n0 + n_local;
            int h = n >> 6, d = n & 63;
            u16x4 v = *(const u16x4*)&Cs[n_local * 132 + half * 64 + l16 * 4];
            *(u16x4*)&Vo[(((size_t)btok * H_ + h) * D_ + d) * S_ + s0 + half * 64 + l16 * 4] = v;
        }
    }
}

// ---------------- Kernel 2: attention, 512 thr, double-buffered K/V ---------
// Q arrives pre-scaled by log2(e)/8 -> exp2 directly on scores.
__global__ __launch_bounds__(512, 3) void attn_direct(
    const unsigned short* __restrict__ Q, const unsigned short* __restrict__ K,
    const unsigned short* __restrict__ Vt, unsigned short* __restrict__ ctx)
{
    __shared__ unsigned short KsD[2][64 * 64];
    __shared__ unsigned short VsD[2][64 * 64];
    __shared__ unsigned short Ps[8][16 * 72];
    const int t = threadIdx.x;
    const int w = t >> 6, lane = t & 63, quad = lane >> 4, l16 = lane & 15;
    const int bh = blockIdx.y;
    const int q0 = blockIdx.x * 128 + w * 16;

    const unsigned short* Qg = Q + ((size_t)bh * S_ + q0) * D_;
    bf16x8 qf[2];
#pragma unroll
    for (int ks = 0; ks < 2; ks++)
        qf[ks] = *(const bf16x8*)(Qg + (size_t)l16 * 64 + ks * 32 + quad * 8);

    bf16x8 ones;
#pragma unroll
    for (int e = 0; e < 8; e++) ones[e] = (short)0x3F80;

    f32x4 zero = {0.f, 0.f, 0.f, 0.f};
    f32x4 acc_o[4];
    f32x4 acc_l = zero;
#pragma unroll
    for (int j = 0; j < 4; j++) acc_o[j] = zero;

    const int tt = t & 255, ksel = t >> 8;
    const int sr = tt >> 2, sc = (tt & 3) * 8;
    const unsigned short* KgL = K  + (size_t)bh * S_ * D_ + (size_t)sr * 64 + ksel * 32 + sc;
    const unsigned short* VgL = Vt + (size_t)bh * D_ * S_ + (size_t)sr * S_ + ksel * 32 + sc;

    g2l16(KgL, &KsD[0][t * 8]);
    g2l16(VgL, &VsD[0][t * 8]);
    __syncthreads();

    int p = 0;
    for (int kt = 0; kt < S_; kt += 64) {
        if (kt + 64 < S_) {
            g2l16(KgL + (size_t)(kt + 64) * 64, &KsD[1 - p][t * 8]);
            g2l16(VgL + (kt + 64),              &VsD[1 - p][t * 8]);
        }

        f32x4 sc4[4];
#pragma unroll
        for (int j = 0; j < 4; j++) sc4[j] = zero;
#pragma unroll
        for (int ks = 0; ks < 2; ks++) {
#pragma unroll
            for (int j = 0; j < 4; j++) {
                bf16x8 kf = *(const bf16x8*)&KsD[p][ks * 2048 + (j * 16 + l16) * 32 + quad * 8];
                sc4[j] = mfma16(qf[ks], kf, sc4[j]);
            }
        }
#pragma unroll
        for (int j = 0; j < 4; j++)
#pragma unroll
            for (int r = 0; r < 4; r += 2) {
                float pa = __builtin_amdgcn_exp2f(sc4[j][r]);
                float pb = __builtin_amdgcn_exp2f(sc4[j][r + 1]);
                unsigned int u = pk2bf(pa, pb);
                Ps[w][(quad * 4 + r)     * 72 + j * 16 + l16] = (unsigned short)u;
                Ps[w][(quad * 4 + r + 1) * 72 + j * 16 + l16] = (unsigned short)(u >> 16);
            }
#pragma unroll
        for (int ks = 0; ks < 2; ks++) {
            bf16x8 pf = *(const bf16x8*)&Ps[w][l16 * 72 + ks * 32 + quad * 8];
#pragma unroll
            for (int jd = 0; jd < 4; jd++) {
                bf16x8 vf = *(const bf16x8*)&VsD[p][ks * 2048 + (jd * 16 + l16) * 32 + quad * 8];
                acc_o[jd] = mfma16(pf, vf, acc_o[jd]);
            }
            acc_l = mfma16(pf, ones, acc_l);
        }

        __syncthreads();
        p ^= 1;
    }

    const int b = bh >> 4, h = bh & 15;
    f32x4 rl;
#pragma unroll
    for (int r = 0; r < 4; r++) rl[r] = 1.0f / acc_l[r];
#pragma unroll
    for (int jd = 0; jd < 4; jd++)
#pragma unroll
        for (int r = 0; r < 4; r++) {
            int qrow = q0 + quad * 4 + r;
            int col = h * 64 + jd * 16 + l16;
            ctx[((size_t)b * S_ + qrow) * E_ + col] = f2bf(acc_o[jd][r] * rl[r]);
        }
}

// ---------------- Kernel 3: output projection (bf16, g2l16) -----------------
__global__ __launch_bounds__(256, 4) void out_bf(
    const unsigned short* __restrict__ Cx, const unsigned short* __restrict__ Wob,
    const float* __restrict__ bo, float* __restrict__ out)
{
    __shared__ unsigned short As[128 * 32];
    __shared__ unsigned short Bs[64 * 32];
    const int t = threadIdx.x;
    const int w = t >> 6, lane = t & 63, quad = lane >> 4, l16 = lane & 15;
    const int m0 = blockIdx.y * 128, n0 = blockIdx.x * 64;
    const int wr = w * 32;
    const int r4 = t >> 2, c8 = (t & 3) * 8;
    const unsigned short* Ag = Cx  + (size_t)(m0 + r4) * E_ + c8;
    const unsigned short* Bg = Wob + (size_t)(n0 + r4) * E_ + c8;

    f32x4 zero = {0.f, 0.f, 0.f, 0.f};
    f32x4 acc[2][4];
#pragma unroll
    for (int i = 0; i < 2; i++)
#pragma unroll
        for (int j = 0; j < 4; j++) acc[i][j] = zero;

    for (int kt = 0; kt < E_; kt += 32) {
        __syncthreads();
        g2l16(Ag + kt,           &As[t * 8]);
        g2l16(Ag + 64 * E_ + kt, &As[t * 8 + 2048]);
        g2l16(Bg + kt,           &Bs[t * 8]);
        __syncthreads();
        bf16x8 af[2], bfr[4];
#pragma unroll
        for (int i = 0; i < 2; i++)
            af[i] = *(const bf16x8*)&As[(wr + i * 16 + l16) * 32 + quad * 8];
#pragma unroll
        for (int j = 0; j < 4; j++)
            bfr[j] = *(const bf16x8*)&Bs[(j * 16 + l16) * 32 + quad * 8];
#pragma unroll
        for (int i = 0; i < 2; i++)
#pragma unroll
            for (int j = 0; j < 4; j++)
                acc[i][j] = mfma16(af[i], bfr[j], acc[i][j]);
    }

#pragma unroll
    for (int j = 0; j < 4; j++) {
        int n = n0 + j * 16 + l16;
        float bvv = bo[n];
#pragma unroll
        for (int i = 0; i < 2; i++) {
            int mrow = m0 + wr + i * 16 + quad * 4;
#pragma unroll
            for (int r = 0; r < 4; r++)
                out[(size_t)(mrow + r) * E_ + n] = acc[i][j][r] + bvv;
        }
    }
}

// ================= f32 fallback (ws too small for bf16 path) =================
__global__ __launch_bounds__(256, 3) void qkv_rope_f32(
    const float* __restrict__ X,
    const float* __restrict__ Wq, const float* __restrict__ Wk,
    const float* __restrict__ Wv,
    const float* __restrict__ bq, const float* __restrict__ bk,
    const float* __restrict__ bv,
    unsigned short* __restrict__ Qo, unsigned short* __restrict__ Ko,
    unsigned short* __restrict__ Vo)
{
    __shared__ __align__(16) unsigned char lds_raw[128 * 132 * 2];
    unsigned short* As = (unsigned short*)lds_raw;
    unsigned short* Bs = (unsigned short*)(lds_raw + 8192);
    unsigned short* Cs = (unsigned short*)lds_raw;

    const int t = threadIdx.x;
    const int w = t >> 6, lane = t & 63, quad = lane >> 4, l16 = lane & 15;
    const int wr = (w >> 1) * 64, wc = (w & 1) * 64;
    const int n0 = blockIdx.x * 128, m0 = blockIdx.y * 128;
    const int z = blockIdx.z;
    const float* W    = (z == 0) ? Wq : (z == 1) ? Wk : Wv;
    const float* bias = (z == 0) ? bq : (z == 1) ? bk : bv;

    const int r4 = t >> 2, c8 = (t & 3) * 8;
    const int st = r4 * PT + c8;
    const float* Ag = X + (size_t)(m0 + r4) * E_ + c8;
    const float* Bg = W + (size_t)(n0 + r4) * E_ + c8;

    f32x4 zero = {0.f, 0.f, 0.f, 0.f};
    f32x4 acc[4][4];
#pragma unroll
    for (int i = 0; i < 4; i++)
#pragma unroll
        for (int j = 0; j < 4; j++) acc[i][j] = zero;

    for (int kt = 0; kt < E_; kt += 32) {
        bf16x8 a0 = cvt8(Ag + kt);
        bf16x8 a1 = cvt8(Ag + 64 * E_ + kt);
        bf16x8 b0 = cvt8(Bg + kt);
        bf16x8 b1 = cvt8(Bg + 64 * E_ + kt);
        __syncthreads();
        *(bf16x8*)&As[st]           = a0;
        *(bf16x8*)&As[st + 64 * PT] = a1;
        *(bf16x8*)&Bs[st]           = b0;
        *(bf16x8*)&Bs[st + 64 * PT] = b1;
        __syncthreads();
        bf16x8 af[4], bfr[4];
#pragma unroll
        for (int i = 0; i < 4; i++)
            af[i] = *(const bf16x8*)&As[(wr + i * 16 + l16) * PT + quad * 8];
#pragma unroll
        for (int j = 0; j < 4; j++)
            bfr[j] = *(const bf16x8*)&Bs[(wc + j * 16 + l16) * PT + quad * 8];
#pragma unroll
        for (int i = 0; i < 4; i++)
#pragma unroll
            for (int j = 0; j < 4; j++)
                acc[i][j] = mfma16(af[i], bfr[j], acc[i][j]);
    }

    __syncthreads();
    const int seg = quad;
    if (z < 2) {
        const float C = -0.41524101186091903f;
        const float INV2PI = 0.15915494309189535f;
        const float qscale = (z == 0) ? SCLQ : 1.0f;
#pragma unroll
        for (int j = 0; j < 4; j++) {
            int n_local = wc + j * 16 + l16;
            int n = n0 + n_local;
            int d = n & 63, f = d >> 1;
            float inv_rev = exp2f(C * (float)f) * INV2PI;
            float bvv = bias[n];
            float sgn = (d & 1) ? 1.f : -1.f;
#pragma unroll
            for (int i = 0; i < 4; i++) {
                int mb = wr + i * 16 + quad * 4;
#pragma unroll
                for (int r = 0; r < 4; r++) {
                    int m = m0 + mb + r;
                    int s = m & (S_ - 1);
                    float val = acc[i][j][r] + bvv;
                    float oth = __shfl_xor(val, 1);
                    float rev = (float)s * inv_rev;
                    float fr = rev - rintf(rev);
                    float sn = __builtin_amdgcn_sinf(fr);
                    float cs = __builtin_amdgcn_cosf(fr);
                    Cs[(mb + r) * 132 + n_local] =
                        f2bf((val * cs + sgn * oth * sn) * qscale);
                }
            }
        }
        __syncthreads();
        unsigned short* Out = (z == 0) ? Qo : Ko;
        const int btok = m0 >> 11;
        const int half = seg & 1;
#pragma unroll
        for (int it = 0; it < 16; it++) {
            int m_local = it * 8 + w * 2 + (seg >> 1);
            int s = (m0 + m_local) & (S_ - 1);
            int h = (n0 + half * 64) >> 6;
            u16x4 v = *(const u16x4*)&Cs[m_local * 132 + half * 64 + l16 * 4];
            *(u16x4*)&Out[(((size_t)btok * H_ + h) * S_ + s) * D_ + l16 * 4] = v;
        }
    } else {
#pragma unroll
        for (int j = 0; j < 4; j++) {
            int n_local = wc + j * 16 + l16;
            float bvv = bias[n0 + n_local];
#pragma unroll
            for (int i = 0; i < 4; i++) {
                int mb = wr + i * 16 + quad * 4;
#pragma unroll
                for (int r = 0; r < 4; r++)
                    Cs[n_local * 132 + mb + r] = f2bf(acc[i][j][r] + bvv);
            }
        }
        __syncthreads();
        const int btok = m0 >> 11;
        const int s0 = m0 & (S_ - 1);
        const int half = seg & 1;
#pragma unroll
        for (int it = 0; it < 16; it++) {
            int n_local = it * 8 + w * 2 + (seg >> 1);
            int n = n0 + n_local;
            int h = n >> 6, d = n & 63;
            u16x4 v = *(const u16x4*)&Cs[n_local * 132 + half * 64 + l16 * 4];
            *(u16x4*)&Vo[(((size_t)btok * H_ + h) * D_ + d) * S_ + s0 + half * 64 + l16 * 4] = v;
        }
    }
}

__global__ __launch_bounds__(256, 2) void out_f32(
    const unsigned short* __restrict__ Cx, const float* __restrict__ Wo,
    const float* __restrict__ bo, float* __restrict__ out)
{
    __shared__ unsigned short As[128 * PT];
    __shared__ unsigned short Bs[64 * PT];
    const int t = threadIdx.x;
    const int w = t >> 6, lane = t & 63, quad = lane >> 4, l16 = lane & 15;
    const int m0 = blockIdx.y * 128, n0 = blockIdx.x * 64;
    const int wr = w * 32;
    const int r4 = t >> 2, c8 = (t & 3) * 8;
    const int st = r4 * PT + c8;
    const unsigned short* Ag = Cx + (size_t)(m0 + r4) * E_ + c8;
    const float*          Bg = Wo + (size_t)(n0 + (r4 & 63)) * E_ + c8;

    f32x4 zero = {0.f, 0.f, 0.f, 0.f};
    f32x4 acc[2][4];
#pragma unroll
    for (int i = 0; i < 2; i++)
#pragma unroll
        for (int j = 0; j < 4; j++) acc[i][j] = zero;

    for (int kt = 0; kt < E_; kt += 32) {
        bf16x8 a0 = *(const bf16x8*)(Ag + kt);
        bf16x8 a1 = *(const bf16x8*)(Ag + 64 * E_ + kt);
        bf16x8 b0 = cvt8(Bg + kt);
        __syncthreads();
        *(bf16x8*)&As[st]           = a0;
        *(bf16x8*)&As[st + 64 * PT] = a1;
        *(bf16x8*)&Bs[st]           = b0;
        __syncthreads();
        bf16x8 af[2], bfr[4];
#pragma unroll
        for (int i = 0; i < 2; i++)
            af[i] = *(const bf16x8*)&As[(wr + i * 16 + l16) * PT + quad * 8];
#pragma unroll
        for (int j = 0; j < 4; j++)
            bfr[j] = *(const bf16x8*)&Bs[(j * 16 + l16) * PT + quad * 8];
#pragma unroll
        for (int i = 0; i < 2; i++)
#pragma unroll
            for (int j = 0; j < 4; j++)
                acc[i][j] = mfma16(af[i], bfr[j], acc[i][j]);
    }

#pragma unroll
    for (int j = 0; j < 4; j++) {
        int n = n0 + j * 16 + l16;
        float bvv = bo[n];
#pragma unroll
        for (int i = 0; i < 2; i++) {
            int mrow = m0 + wr + i * 16 + quad * 4;
#pragma unroll
            for (int r = 0; r < 4; r++)
                out[(size_t)(mrow + r) * E_ + n] = acc[i][j][r] + bvv;
        }
    }
}

extern "C" void kernel_launch(void* const* d_in, const int* in_sizes, int n_in,
                              void* d_out, int out_size, void* d_ws, size_t ws_size,
                              hipStream_t stream) {
    const float* X  = (const float*)d_in[0];
    const float* Wq = (const float*)d_in[1];
    const float* bq = (const float*)d_in[2];
    const float* Wk = (const float*)d_in[3];
    const float* bk = (const float*)d_in[4];
    const float* Wv = (const float*)d_in[5];
    const float* bv = (const float*)d_in[6];
    const float* Wo = (const float*)d_in[7];
    const float* bo = (const float*)d_in[8];
    float* outp = (float*)d_out;

    const size_t TN = (size_t)B_ * H_ * S_ * D_;
    const size_t need_f32 = 4 * TN * sizeof(unsigned short);
    const size_t need_bf  = 5 * TN * sizeof(unsigned short) + 2 * 65536 * sizeof(float);
    if (ws_size < need_f32) return;

    unsigned short* Qb = (unsigned short*)d_ws;
    unsigned short* Kb = Qb + TN;
    unsigned short* Vb = Kb + TN;

    if (ws_size >= need_bf) {
        unsigned short* Xb = Vb + TN;   // aliased by Cx after qkv (stream-ordered)
        unsigned short* Wb = Xb + TN;
        float* tab = (float*)(Wb + 4 * (size_t)(E_ * E_));
        unsigned short* Cx = Xb;

        cvt_kernel<<<dim3(2048, 6), 256, 0, stream>>>(X, Wq, Wk, Wv, Wo, Xb, Wb, tab);
        qkv_rope_bf<<<dim3(E_ / 128, M_ / 128, 3), 256, 0, stream>>>(
            Xb, Wb, bq, bk, bv, tab, Qb, Kb, Vb);
        attn_direct<<<dim3(S_ / 128, B_ * H_), 512, 0, stream>>>(Qb, Kb, Vb, Cx);
        out_bf<<<dim3(E_ / 64, M_ / 128), 256, 0, stream>>>(
            Cx, Wb + 3 * (size_t)(E_ * E_), bo, outp);
    } else {
        unsigned short* Cx = Vb + TN;
        qkv_rope_f32<<<dim3(E_ / 128, M_ / 128, 3), 256, 0, stream>>>(
            X, Wq, Wk, Wv, bq, bk, bv, Qb, Kb, Vb);
        attn_direct<<<dim3(S_ / 128, B_ * H_), 512, 0, stream>>>(Qb, Kb, Vb, Cx);
        out_f32<<<dim3(E_ / 64, M_ / 128), 256, 0, stream>>>(Cx, Wo, bo, outp);
    }
}